// Round 6
// baseline (231.818 us; speedup 1.0000x reference)
//
#include <hip/hip_runtime.h>
#include <hip/hip_bf16.h>

// B=4, S=2048, TEXT_DIM=768, VISION_DIM=768, HIDDEN=512, HEADS=8, HEAD_DIM=64
#define BATCH 4
#define SEQ 2048
#define TDIM 768
#define VDIM 768
#define HID 512
#define NHEADS 8
#define HDIM 64
#define MROWS (BATCH * SEQ)   // 8192
#define NQKV (3 * HID)        // 1536

typedef unsigned short ushort_t;
typedef __attribute__((ext_vector_type(8))) short short8;
typedef __attribute__((ext_vector_type(4))) short short4v;
typedef __attribute__((ext_vector_type(4))) float floatx4;

// 0.125 * log2(e): folded into Q so softmax uses exp2
#define QSCALE 0.18033688011112042f

__device__ __forceinline__ ushort_t bf16_rne(float f) {
    unsigned int u = __float_as_uint(f);
    u = (u + 0x7fffu + ((u >> 16) & 1u)) >> 16;
    return (ushort_t)u;
}

__device__ __forceinline__ void async16(const ushort_t* g, ushort_t* l) {
    __builtin_amdgcn_global_load_lds(
        (const __attribute__((address_space(1))) unsigned int*)g,
        (__attribute__((address_space(3))) unsigned int*)l, 16, 0, 0);
}

// ---------------------------------------------------------------------------
// Pre-pass A: X fp32 -> bf16 (8192x768)
// ---------------------------------------------------------------------------
__global__ __launch_bounds__(256) void conv_x(const float* __restrict__ X,
                                              ushort_t* __restrict__ Xb)
{
    const int i = (blockIdx.x * 256 + threadIdx.x) * 4;
    const floatx4 v = *(const floatx4*)(X + i);
    short4v o;
#pragma unroll
    for (int j = 0; j < 4; ++j) o[j] = (short)bf16_rne(v[j]);
    *(short4v*)(Xb + i) = o;
}

// ---------------------------------------------------------------------------
// Pre-pass B: weight transposes -> bf16 [N][K].
// ---------------------------------------------------------------------------
__global__ __launch_bounds__(256) void transp_w(
    const float* __restrict__ Wq, const float* __restrict__ Wk,
    const float* __restrict__ Wv, const float* __restrict__ Wo,
    ushort_t* __restrict__ Wqkvt, ushort_t* __restrict__ Wot)
{
    __shared__ float tile[32][33];
    const int z = blockIdx.z;
    const float* src;
    ushort_t* dst;
    int R, C;
    if (z < 3) {
        src = (z == 0) ? Wq : (z == 1) ? Wk : Wv;
        dst = Wqkvt + (size_t)z * HID * TDIM;
        R = TDIM; C = HID;
    } else {
        src = Wo; dst = Wot; R = HID; C = VDIM;
    }
    const int tx = threadIdx.x & 31, ty = threadIdx.x >> 5;  // 32 x 8
    const int c0 = blockIdx.x * 32, r0 = blockIdx.y * 32;
    if (c0 >= C || r0 >= R) return;
#pragma unroll
    for (int i = 0; i < 4; ++i)
        tile[ty + i * 8][tx] = src[(size_t)(r0 + ty + i * 8) * C + c0 + tx];
    __syncthreads();
#pragma unroll
    for (int i = 0; i < 4; ++i)
        dst[(size_t)(c0 + ty + i * 8) * R + r0 + tx] = bf16_rne(tile[tx][ty + i * 8]);
}

// ---------------------------------------------------------------------------
// m97-style bf16 MFMA GEMM mainloop: C(128x128) = A[M][K] x Bt[N][K]^T.
// ---------------------------------------------------------------------------
template<int KD, bool SWAPPED>
__device__ __forceinline__ void gemm128(
    const ushort_t* __restrict__ A, const ushort_t* __restrict__ Bt,
    int m0, int n0, ushort_t* As, ushort_t* Bs, floatx4 (&acc)[4][4])
{
    const int tid  = threadIdx.x;
    const int lane = tid & 63;
    const int w    = tid >> 6;
    const int l15  = lane & 15;
    const int quad = lane >> 4;
    const int wrow = w >> 1;
    const int wcol = w & 1;

    const int srow = lane >> 3;        // 0..7
    const int scol = (lane & 7) * 8;   // k elem offset

    const ushort_t* ga = A  + (size_t)(m0 + w * 32 + srow) * KD + scol;
    const ushort_t* gb = Bt + (size_t)(n0 + w * 32 + srow) * KD + scol;
    ushort_t* la = As + (w * 32) * 64;
    ushort_t* lb = Bs + (w * 32) * 64;

    for (int kt = 0; kt < KD; kt += 64) {
#pragma unroll
        for (int i = 0; i < 4; ++i) {
            async16(ga + (size_t)(i * 8) * KD + kt, la + i * 8 * 64);
            async16(gb + (size_t)(i * 8) * KD + kt, lb + i * 8 * 64);
        }
        __syncthreads();
#pragma unroll
        for (int half = 0; half < 2; ++half) {
            const int kk = half * 32 + quad * 8;
            short8 af[4], bf[4];
#pragma unroll
            for (int t = 0; t < 4; ++t) {
                af[t] = *(const short8*)&As[(wrow * 64 + t * 16 + l15) * 64 + kk];
                bf[t] = *(const short8*)&Bs[(wcol * 64 + t * 16 + l15) * 64 + kk];
            }
#pragma unroll
            for (int mi = 0; mi < 4; ++mi)
#pragma unroll
                for (int ni = 0; ni < 4; ++ni) {
                    if (SWAPPED)
                        acc[mi][ni] = __builtin_amdgcn_mfma_f32_16x16x32_bf16(
                            bf[ni], af[mi], acc[mi][ni], 0, 0, 0);
                    else
                        acc[mi][ni] = __builtin_amdgcn_mfma_f32_16x16x32_bf16(
                            af[mi], bf[ni], acc[mi][ni], 0, 0, 0);
                }
        }
        __syncthreads();
    }
}

// ---------------------------------------------------------------------------
// Kernel 1: QKV projection, bf16 MFMA.
// ---------------------------------------------------------------------------
__global__ __launch_bounds__(256) void qkv_gemm_mfma(
    const ushort_t* __restrict__ Xb, const ushort_t* __restrict__ Wt,
    const float* __restrict__ bq, const float* __restrict__ bk,
    const float* __restrict__ bv,
    ushort_t* __restrict__ Q, ushort_t* __restrict__ K, ushort_t* __restrict__ V)
{
    __shared__ __align__(16) ushort_t As[128 * 64];
    __shared__ __align__(16) ushort_t Bs[128 * 64];

    const int bx = blockIdx.x;          // 0..11
    const int m0 = blockIdx.y * 128;
    const int n0 = bx * 128;
    const int which = bx >> 2;          // 0=Q 1=K 2=V
    const bool isV = (which == 2);

    floatx4 acc[4][4];
#pragma unroll
    for (int i = 0; i < 4; ++i)
#pragma unroll
        for (int j = 0; j < 4; ++j) acc[i][j] = (floatx4)0.0f;

    if (isV) gemm128<TDIM, false>(Xb, Wt, m0, n0, As, Bs, acc);
    else     gemm128<TDIM, true >(Xb, Wt, m0, n0, As, Bs, acc);

    const int lane = threadIdx.x & 63;
    const int w    = threadIdx.x >> 6;
    const int l15  = lane & 15;
    const int quad = lane >> 4;
    const int wrow = w >> 1;
    const int wcol = w & 1;

    if (!isV) {
        const float* bias = (which == 0) ? bq : bk;
        const float scale = (which == 0) ? QSCALE : 1.0f;
        ushort_t* Out = (which == 0) ? Q : K;
#pragma unroll
        for (int mi = 0; mi < 4; ++mi) {
            const int m = m0 + wrow * 64 + mi * 16 + l15;
            const int b = m >> 11;
            const int s = m & 2047;
#pragma unroll
            for (int ni = 0; ni < 4; ++ni) {
                const int c = (n0 - which * HID) + wcol * 64 + ni * 16 + quad * 4;
                const int h = c >> 6;
                const int d0 = c & 63;
                const floatx4 b4 = *(const floatx4*)(bias + c);
                short4v pk;
#pragma unroll
                for (int r = 0; r < 4; ++r)
                    pk[r] = (short)bf16_rne((acc[mi][ni][r] + b4[r]) * scale);
                *(short4v*)&Out[((size_t)(b * NHEADS + h) * SEQ + s) * HDIM + d0] = pk;
            }
        }
    } else {
#pragma unroll
        for (int ni = 0; ni < 4; ++ni) {
            const int c = (n0 - 2 * HID) + wcol * 64 + ni * 16 + l15;
            const int h = c >> 6;
            const int d = c & 63;
            const float b1 = bv[c];
#pragma unroll
            for (int mi = 0; mi < 4; ++mi) {
                const int mb = m0 + wrow * 64 + mi * 16 + quad * 4;
                const int b = mb >> 11;
                const int s0 = mb & 2047;
                short4v pk;
#pragma unroll
                for (int r = 0; r < 4; ++r)
                    pk[r] = (short)bf16_rne(acc[mi][ni][r] + b1);
                *(short4v*)&V[((size_t)(b * NHEADS + h) * HDIM + d) * SEQ + s0] = pk;
            }
        }
    }
}

// ---------------------------------------------------------------------------
// Kernel 2: MFMA flash attention v4 (bf16 in/out).
// 512 threads = 8 waves.  Q-tile 128 rows.  Wave w: q-set (w&3)*32..+31,
// kk-half (w>>2).  No-max softmax makes attention additive over kk, so the
// two wave groups process disjoint kk halves and combine O/l once at end.
// Per iter: stage K[128][64] + V^T[64][128] (single-buffered, reg-prefetch).
// LDS = 16K (K) + 16K (V) + 32K (P strips) = 64 KB -> 2 blocks/CU = 16 w/CU.
// XOR swizzle (16B granule, key=row&7) -> uniform bank slots, ~0 conflicts.
// ---------------------------------------------------------------------------
#define FA_LDS_V 8192     // ushort offset of V region
#define FA_LDS_P 16384    // ushort offset of P region

__global__ __launch_bounds__(512, 4) void flash_attn_mfma(
    const ushort_t* __restrict__ Q, const ushort_t* __restrict__ K,
    const ushort_t* __restrict__ Vt, ushort_t* __restrict__ Att)
{
    __shared__ __align__(16) ushort_t lds[32768];   // 64 KB exactly

    const int tid  = threadIdx.x;
    const int lane = tid & 63;
    const int w    = tid >> 6;     // 0..7
    const int wg   = w >> 2;       // kk-half group
    const int wq   = w & 3;        // q-set
    const int l15  = lane & 15;
    const int quad = lane >> 4;
    const int key  = l15 & 7;      // swizzle key for frag rows (row&7 == l15&7)

    const int bh = blockIdx.x;     // XCD-locality: all q-tiles of bh on one XCD
    const int b  = bh >> 3;
    const int h  = bh & 7;
    const int q0 = blockIdx.y * 128;

    const ushort_t* Qb = Q  + (size_t)bh * SEQ * HDIM;
    const ushort_t* Kb = K  + (size_t)bh * SEQ * HDIM;
    const ushort_t* Vb = Vt + (size_t)bh * HDIM * SEQ;

    // Q B-frags for q = q0 + wq*32 + {l15, 16+l15}
    short8 qfA0, qfA1, qfB0, qfB1;
    {
        const ushort_t* qa = Qb + (size_t)(q0 + wq * 32 + l15) * HDIM + quad * 8;
        qfA0 = *(const short8*)(qa);
        qfA1 = *(const short8*)(qa + 32);
        qfB0 = *(const short8*)(qa + 16 * HDIM);
        qfB1 = *(const short8*)(qa + 16 * HDIM + 32);
    }

    float lA = 0.f, lB = 0.f;
    floatx4 ofA[4], ofB[4];
#pragma unroll
    for (int t = 0; t < 4; ++t) { ofA[t] = (floatx4)0.0f; ofB[t] = (floatx4)0.0f; }

    // ---- staging maps (512 threads; 2 K granules + 2 V granules each) ----
    const int krow = tid >> 3;        // 0..63 (and +64)
    const int kg   = tid & 7;
    const int vrow = tid >> 4;        // 0..31 (and +32)
    const int vg   = tid & 15;

    const ushort_t* gK = Kb + (size_t)krow * HDIM + kg * 8;
    const ushort_t* gV = Vb + (size_t)vrow * SEQ + vg * 8;

    const int ka0 = krow * 64 + (kg ^ (krow & 7)) * 8;
    const int ka1 = ka0 + 64 * 64;                       // (krow+64)&7 == krow&7
    const int va0 = FA_LDS_V + vrow * 128 + (((vg & 7) ^ (vrow & 7)) | (vg & 8)) * 8;
    const int va1 = va0 + 32 * 128;

    short8 kr0 = *(const short8*)(gK);
    short8 kr1 = *(const short8*)(gK + (size_t)64 * HDIM);
    short8 vr0 = *(const short8*)(gV);
    short8 vr1 = *(const short8*)(gV + (size_t)32 * SEQ);

    ushort_t* Pw = lds + FA_LDS_P + w * 2048;   // [32 q][64 kk] swizzled
    const int kkrow0 = wg * 64;                 // this group's K rows
    const int vgb    = wg * 8;                  // this group's V granule base

    for (int it = 0; it < 16; ++it) {
        if (it) __syncthreads();
        *(short8*)&lds[ka0] = kr0;
        *(short8*)&lds[ka1] = kr1;
        *(short8*)&lds[va0] = vr0;
        *(short8*)&lds[va1] = vr1;
        __syncthreads();

        if (it < 15) {
            const int kt = (it + 1) * 128;
            kr0 = *(const short8*)(gK + (size_t)kt * HDIM);
            kr1 = *(const short8*)(gK + (size_t)(kt + 64) * HDIM);
            vr0 = *(const short8*)(gV + kt);
            vr1 = *(const short8*)(gV + (size_t)32 * SEQ + kt);
        }

        // ---- S^T = K . Q^T for both q sets ----
        floatx4 saccA[4], saccB[4];
#pragma unroll
        for (int t = 0; t < 4; ++t) {
            const int rbase = (kkrow0 + t * 16 + l15) * 64;
            const short8 kf0 = *(const short8*)&lds[rbase + (quad ^ key) * 8];
            const short8 kf1 = *(const short8*)&lds[rbase + ((quad + 4) ^ key) * 8];
            floatx4 a = (floatx4)0.0f, bb = (floatx4)0.0f;
            a  = __builtin_amdgcn_mfma_f32_16x16x32_bf16(kf0, qfA0, a, 0, 0, 0);
            a  = __builtin_amdgcn_mfma_f32_16x16x32_bf16(kf1, qfA1, a, 0, 0, 0);
            bb = __builtin_amdgcn_mfma_f32_16x16x32_bf16(kf0, qfB0, bb, 0, 0, 0);
            bb = __builtin_amdgcn_mfma_f32_16x16x32_bf16(kf1, qfB1, bb, 0, 0, 0);
            saccA[t] = a;
            saccB[t] = bb;
        }

        // ---- no-max softmax + bf16 pack into swizzled P strips ----
        float rsA = 0.f, rsB = 0.f;
#pragma unroll
        for (int t = 0; t < 4; ++t) {
            float pa[4], pb[4];
#pragma unroll
            for (int r = 0; r < 4; ++r) {
                pa[r] = exp2f(saccA[t][r]); rsA += pa[r];
                pb[r] = exp2f(saccB[t][r]); rsB += pb[r];
            }
            // P granule g = 2t + (quad>>1); phys = g ^ key; half = quad&1
            const int pofs = ((2 * t + (quad >> 1)) ^ key) * 8 + (quad & 1) * 4;
            {
                const unsigned u0 = __float_as_uint(pa[0]) + 0x8000u;
                const unsigned u1 = __float_as_uint(pa[1]) + 0x8000u;
                const unsigned u2 = __float_as_uint(pa[2]) + 0x8000u;
                const unsigned u3 = __float_as_uint(pa[3]) + 0x8000u;
                const unsigned lo = __builtin_amdgcn_perm(u1, u0, 0x07060302u);
                const unsigned hi = __builtin_amdgcn_perm(u3, u2, 0x07060302u);
                *(unsigned long long*)&Pw[l15 * 64 + pofs] =
                    ((unsigned long long)hi << 32) | lo;
            }
            {
                const unsigned u0 = __float_as_uint(pb[0]) + 0x8000u;
                const unsigned u1 = __float_as_uint(pb[1]) + 0x8000u;
                const unsigned u2 = __float_as_uint(pb[2]) + 0x8000u;
                const unsigned u3 = __float_as_uint(pb[3]) + 0x8000u;
                const unsigned lo = __builtin_amdgcn_perm(u1, u0, 0x07060302u);
                const unsigned hi = __builtin_amdgcn_perm(u3, u2, 0x07060302u);
                *(unsigned long long*)&Pw[(16 + l15) * 64 + pofs] =
                    ((unsigned long long)hi << 32) | lo;
            }
        }
        lA += rsA;
        lB += rsB;
        asm volatile("s_waitcnt lgkmcnt(0)" ::: "memory");

        const short8 pfA0 = *(const short8*)&Pw[l15 * 64 + (quad ^ key) * 8];
        const short8 pfA1 = *(const short8*)&Pw[l15 * 64 + ((quad + 4) ^ key) * 8];
        const short8 pfB0 = *(const short8*)&Pw[(16 + l15) * 64 + (quad ^ key) * 8];
        const short8 pfB1 = *(const short8*)&Pw[(16 + l15) * 64 + ((quad + 4) ^ key) * 8];

        // ---- O^T += V^T . P^T ----
#pragma unroll
        for (int t = 0; t < 4; ++t) {
            const int vbase = FA_LDS_V + (t * 16 + l15) * 128;
            const short8 vf0 = *(const short8*)&lds[vbase + (vgb | (quad ^ key)) * 8];
            const short8 vf1 = *(const short8*)&lds[vbase + (vgb | ((quad + 4) ^ key)) * 8];
            ofA[t] = __builtin_amdgcn_mfma_f32_16x16x32_bf16(vf0, pfA0, ofA[t], 0, 0, 0);
            ofA[t] = __builtin_amdgcn_mfma_f32_16x16x32_bf16(vf1, pfA1, ofA[t], 0, 0, 0);
            ofB[t] = __builtin_amdgcn_mfma_f32_16x16x32_bf16(vf0, pfB0, ofB[t], 0, 0, 0);
            ofB[t] = __builtin_amdgcn_mfma_f32_16x16x32_bf16(vf1, pfB1, ofB[t], 0, 0, 0);
        }
    }

    // ---- reduce l across quads within each wave ----
    lA += __shfl_xor(lA, 16); lA += __shfl_xor(lA, 32);
    lB += __shfl_xor(lB, 16); lB += __shfl_xor(lB, 32);

    // ---- combine the two kk-half groups through LDS ----
    __syncthreads();
    float* ex  = (float*)lds;                    // reuse K+V regions (8192 floats)
    float* lex = (float*)(lds + FA_LDS_P);       // reuse P region
    if (wg == 1) {
#pragma unroll
        for (int t = 0; t < 4; ++t)
#pragma unroll
            for (int r = 0; r < 4; ++r) {
                ex[(wq * 32 + t * 4 + r) * 64 + lane]      = ofA[t][r];
                ex[(wq * 32 + 16 + t * 4 + r) * 64 + lane] = ofB[t][r];
            }
        if (quad == 0) {
            lex[wq * 32 + l15]      = lA;
            lex[wq * 32 + 16 + l15] = lB;
        }
    }
    __syncthreads();
    if (wg == 0) {
#pragma unroll
        for (int t = 0; t < 4; ++t)
#pragma unroll
            for (int r = 0; r < 4; ++r) {
                ofA[t][r] += ex[(wq * 32 + t * 4 + r) * 64 + lane];
                ofB[t][r] += ex[(wq * 32 + 16 + t * 4 + r) * 64 + lane];
            }
        lA += lex[wq * 32 + l15];
        lB += lex[wq * 32 + 16 + l15];
        const float invA = 1.f / lA;
        const float invB = 1.f / lB;

        const int sA = q0 + wq * 32 + l15;
        ushort_t* arowA = Att + ((size_t)(b * SEQ + sA)) * HID + h * HDIM;
        ushort_t* arowB = arowA + (size_t)16 * HID;
#pragma unroll
        for (int t = 0; t < 4; ++t) {
            short4v pkA, pkB;
#pragma unroll
            for (int r = 0; r < 4; ++r) {
                pkA[r] = (short)bf16_rne(ofA[t][r] * invA);
                pkB[r] = (short)bf16_rne(ofB[t][r] * invB);
            }
            *(short4v*)&arowA[t * 16 + quad * 4] = pkA;
            *(short4v*)&arowB[t * 16 + quad * 4] = pkB;
        }
    }
}

// ---------------------------------------------------------------------------
// Kernel 3: output projection, bf16 MFMA.
// ---------------------------------------------------------------------------
__global__ __launch_bounds__(256) void out_gemm_mfma(
    const ushort_t* __restrict__ Attb, const ushort_t* __restrict__ Wot,
    const float* __restrict__ bo, float* __restrict__ Y)
{
    __shared__ __align__(16) ushort_t As[128 * 64];
    __shared__ __align__(16) ushort_t Bs[128 * 64];

    const int m0 = blockIdx.y * 128;
    const int n0 = blockIdx.x * 128;

    floatx4 acc[4][4];
#pragma unroll
    for (int i = 0; i < 4; ++i)
#pragma unroll
        for (int j = 0; j < 4; ++j) acc[i][j] = (floatx4)0.0f;

    gemm128<HID, true>(Attb, Wot, m0, n0, As, Bs, acc);

    const int lane = threadIdx.x & 63;
    const int w    = threadIdx.x >> 6;
    const int l15  = lane & 15;
    const int quad = lane >> 4;
    const int wrow = w >> 1;
    const int wcol = w & 1;

#pragma unroll
    for (int mi = 0; mi < 4; ++mi) {
        const int m = m0 + wrow * 64 + mi * 16 + l15;
#pragma unroll
        for (int ni = 0; ni < 4; ++ni) {
            const int nb = n0 + wcol * 64 + ni * 16 + quad * 4;
            const floatx4 b4 = *(const floatx4*)(bo + nb);
            floatx4 o;
#pragma unroll
            for (int r = 0; r < 4; ++r) o[r] = acc[mi][ni][r] + b4[r];
            *(floatx4*)&Y[(size_t)m * VDIM + nb] = o;
        }
    }
}

// ---------------------------------------------------------------------------
extern "C" void kernel_launch(void* const* d_in, const int* in_sizes, int n_in,
                              void* d_out, int out_size, void* d_ws, size_t ws_size,
                              hipStream_t stream)
{
    const float* text = (const float*)d_in[0];
    const float* Wq = (const float*)d_in[1];
    const float* bq = (const float*)d_in[2];
    const float* Wk = (const float*)d_in[3];
    const float* bk = (const float*)d_in[4];
    const float* Wv = (const float*)d_in[5];
    const float* bv = (const float*)d_in[6];
    const float* Wo = (const float*)d_in[7];
    const float* bo = (const float*)d_in[8];
    float* out = (float*)d_out;

    // ws layout (bf16): Xb | Wqkvt | Wot | Q | K | Vt | Attb  (~49 MB)
    ushort_t* Xb    = (ushort_t*)d_ws;
    ushort_t* Wqkvt = Xb + (size_t)MROWS * TDIM;
    ushort_t* Wot   = Wqkvt + (size_t)NQKV * TDIM;
    ushort_t* Qw    = Wot + (size_t)VDIM * HID;
    ushort_t* Kw    = Qw + (size_t)MROWS * HID;
    ushort_t* Vtw   = Kw + (size_t)MROWS * HID;
    ushort_t* Attb  = Vtw + (size_t)MROWS * HID;

    conv_x<<<dim3(MROWS * TDIM / 1024), 256, 0, stream>>>(text, Xb);
    transp_w<<<dim3(24, 24, 4), 256, 0, stream>>>(Wq, Wk, Wv, Wo, Wqkvt, Wot);
    qkv_gemm_mfma<<<dim3(12, 64), 256, 0, stream>>>(Xb, Wqkvt, bq, bk, bv, Qw, Kw, Vtw);
    flash_attn_mfma<<<dim3(32, 16), 512, 0, stream>>>(Qw, Kw, Vtw, Attb);
    out_gemm_mfma<<<dim3(6, 64), 256, 0, stream>>>(Attb, Wot, bo, out);
}

// Round 7
// 214.379 us; speedup vs baseline: 1.0813x; 1.0813x over previous
//
#include <hip/hip_runtime.h>
#include <hip/hip_bf16.h>

// B=4, S=2048, TEXT_DIM=768, VISION_DIM=768, HIDDEN=512, HEADS=8, HEAD_DIM=64
#define BATCH 4
#define SEQ 2048
#define TDIM 768
#define VDIM 768
#define HID 512
#define NHEADS 8
#define HDIM 64
#define MROWS (BATCH * SEQ)   // 8192
#define NQKV (3 * HID)        // 1536

typedef unsigned short ushort_t;
typedef __attribute__((ext_vector_type(8))) short short8;
typedef __attribute__((ext_vector_type(4))) short short4v;
typedef __attribute__((ext_vector_type(4))) float floatx4;

// 0.125 * log2(e): folded into Q so softmax uses exp2
#define QSCALE 0.18033688011112042f

__device__ __forceinline__ ushort_t bf16_rne(float f) {
    unsigned int u = __float_as_uint(f);
    u = (u + 0x7fffu + ((u >> 16) & 1u)) >> 16;
    return (ushort_t)u;
}

__device__ __forceinline__ float bf16_to_f(ushort_t v) {
    return __uint_as_float(((unsigned)v) << 16);
}

__device__ __forceinline__ void async16(const ushort_t* g, ushort_t* l) {
    __builtin_amdgcn_global_load_lds(
        (const __attribute__((address_space(1))) unsigned int*)g,
        (__attribute__((address_space(3))) unsigned int*)l, 16, 0, 0);
}

// ---------------------------------------------------------------------------
// Pre-pass A: X fp32 -> bf16 (8192x768)
// ---------------------------------------------------------------------------
__global__ __launch_bounds__(256) void conv_x(const float* __restrict__ X,
                                              ushort_t* __restrict__ Xb)
{
    const int i = (blockIdx.x * 256 + threadIdx.x) * 4;
    const floatx4 v = *(const floatx4*)(X + i);
    short4v o;
#pragma unroll
    for (int j = 0; j < 4; ++j) o[j] = (short)bf16_rne(v[j]);
    *(short4v*)(Xb + i) = o;
}

// ---------------------------------------------------------------------------
// Pre-pass B: weight transposes -> bf16 [N][K].
// ---------------------------------------------------------------------------
__global__ __launch_bounds__(256) void transp_w(
    const float* __restrict__ Wq, const float* __restrict__ Wk,
    const float* __restrict__ Wv, const float* __restrict__ Wo,
    ushort_t* __restrict__ Wqkvt, ushort_t* __restrict__ Wot)
{
    __shared__ float tile[32][33];
    const int z = blockIdx.z;
    const float* src;
    ushort_t* dst;
    int R, C;
    if (z < 3) {
        src = (z == 0) ? Wq : (z == 1) ? Wk : Wv;
        dst = Wqkvt + (size_t)z * HID * TDIM;
        R = TDIM; C = HID;
    } else {
        src = Wo; dst = Wot; R = HID; C = VDIM;
    }
    const int tx = threadIdx.x & 31, ty = threadIdx.x >> 5;  // 32 x 8
    const int c0 = blockIdx.x * 32, r0 = blockIdx.y * 32;
    if (c0 >= C || r0 >= R) return;
#pragma unroll
    for (int i = 0; i < 4; ++i)
        tile[ty + i * 8][tx] = src[(size_t)(r0 + ty + i * 8) * C + c0 + tx];
    __syncthreads();
#pragma unroll
    for (int i = 0; i < 4; ++i)
        dst[(size_t)(c0 + ty + i * 8) * R + r0 + tx] = bf16_rne(tile[tx][ty + i * 8]);
}

// ---------------------------------------------------------------------------
// m97-style bf16 MFMA GEMM mainloop: C(128x128) = A[M][K] x Bt[N][K]^T.
// ---------------------------------------------------------------------------
template<int KD, bool SWAPPED>
__device__ __forceinline__ void gemm128(
    const ushort_t* __restrict__ A, const ushort_t* __restrict__ Bt,
    int m0, int n0, ushort_t* As, ushort_t* Bs, floatx4 (&acc)[4][4])
{
    const int tid  = threadIdx.x;
    const int lane = tid & 63;
    const int w    = tid >> 6;
    const int l15  = lane & 15;
    const int quad = lane >> 4;
    const int wrow = w >> 1;
    const int wcol = w & 1;

    const int srow = lane >> 3;        // 0..7
    const int scol = (lane & 7) * 8;   // k elem offset

    const ushort_t* ga = A  + (size_t)(m0 + w * 32 + srow) * KD + scol;
    const ushort_t* gb = Bt + (size_t)(n0 + w * 32 + srow) * KD + scol;
    ushort_t* la = As + (w * 32) * 64;
    ushort_t* lb = Bs + (w * 32) * 64;

    for (int kt = 0; kt < KD; kt += 64) {
#pragma unroll
        for (int i = 0; i < 4; ++i) {
            async16(ga + (size_t)(i * 8) * KD + kt, la + i * 8 * 64);
            async16(gb + (size_t)(i * 8) * KD + kt, lb + i * 8 * 64);
        }
        __syncthreads();
#pragma unroll
        for (int half = 0; half < 2; ++half) {
            const int kk = half * 32 + quad * 8;
            short8 af[4], bf[4];
#pragma unroll
            for (int t = 0; t < 4; ++t) {
                af[t] = *(const short8*)&As[(wrow * 64 + t * 16 + l15) * 64 + kk];
                bf[t] = *(const short8*)&Bs[(wcol * 64 + t * 16 + l15) * 64 + kk];
            }
#pragma unroll
            for (int mi = 0; mi < 4; ++mi)
#pragma unroll
                for (int ni = 0; ni < 4; ++ni) {
                    if (SWAPPED)
                        acc[mi][ni] = __builtin_amdgcn_mfma_f32_16x16x32_bf16(
                            bf[ni], af[mi], acc[mi][ni], 0, 0, 0);
                    else
                        acc[mi][ni] = __builtin_amdgcn_mfma_f32_16x16x32_bf16(
                            af[mi], bf[ni], acc[mi][ni], 0, 0, 0);
                }
        }
        __syncthreads();
    }
}

// ---------------------------------------------------------------------------
// Kernel 1: QKV projection, bf16 MFMA.
// ---------------------------------------------------------------------------
__global__ __launch_bounds__(256) void qkv_gemm_mfma(
    const ushort_t* __restrict__ Xb, const ushort_t* __restrict__ Wt,
    const float* __restrict__ bq, const float* __restrict__ bk,
    const float* __restrict__ bv,
    ushort_t* __restrict__ Q, ushort_t* __restrict__ K, ushort_t* __restrict__ V)
{
    __shared__ __align__(16) ushort_t As[128 * 64];
    __shared__ __align__(16) ushort_t Bs[128 * 64];

    const int bx = blockIdx.x;          // 0..11
    const int m0 = blockIdx.y * 128;
    const int n0 = bx * 128;
    const int which = bx >> 2;          // 0=Q 1=K 2=V
    const bool isV = (which == 2);

    floatx4 acc[4][4];
#pragma unroll
    for (int i = 0; i < 4; ++i)
#pragma unroll
        for (int j = 0; j < 4; ++j) acc[i][j] = (floatx4)0.0f;

    if (isV) gemm128<TDIM, false>(Xb, Wt, m0, n0, As, Bs, acc);
    else     gemm128<TDIM, true >(Xb, Wt, m0, n0, As, Bs, acc);

    const int lane = threadIdx.x & 63;
    const int w    = threadIdx.x >> 6;
    const int l15  = lane & 15;
    const int quad = lane >> 4;
    const int wrow = w >> 1;
    const int wcol = w & 1;

    if (!isV) {
        const float* bias = (which == 0) ? bq : bk;
        const float scale = (which == 0) ? QSCALE : 1.0f;
        ushort_t* Out = (which == 0) ? Q : K;
#pragma unroll
        for (int mi = 0; mi < 4; ++mi) {
            const int m = m0 + wrow * 64 + mi * 16 + l15;
            const int b = m >> 11;
            const int s = m & 2047;
#pragma unroll
            for (int ni = 0; ni < 4; ++ni) {
                const int c = (n0 - which * HID) + wcol * 64 + ni * 16 + quad * 4;
                const int h = c >> 6;
                const int d0 = c & 63;
                const floatx4 b4 = *(const floatx4*)(bias + c);
                short4v pk;
#pragma unroll
                for (int r = 0; r < 4; ++r)
                    pk[r] = (short)bf16_rne((acc[mi][ni][r] + b4[r]) * scale);
                *(short4v*)&Out[((size_t)(b * NHEADS + h) * SEQ + s) * HDIM + d0] = pk;
            }
        }
    } else {
#pragma unroll
        for (int ni = 0; ni < 4; ++ni) {
            const int c = (n0 - 2 * HID) + wcol * 64 + ni * 16 + l15;
            const int h = c >> 6;
            const int d = c & 63;
            const float b1 = bv[c];
#pragma unroll
            for (int mi = 0; mi < 4; ++mi) {
                const int mb = m0 + wrow * 64 + mi * 16 + quad * 4;
                const int b = mb >> 11;
                const int s0 = mb & 2047;
                short4v pk;
#pragma unroll
                for (int r = 0; r < 4; ++r)
                    pk[r] = (short)bf16_rne(acc[mi][ni][r] + b1);
                *(short4v*)&V[((size_t)(b * NHEADS + h) * HDIM + d) * SEQ + s0] = pk;
            }
        }
    }
}

// ---------------------------------------------------------------------------
// Kernel 2: MFMA flash attention v5 (bf16 in, bf16 partials out).
// 512 threads = 8 waves, each owning 32 q columns -> Q-tile = 256 rows.
// Grid (32 bh, 8 q-tiles, 2 kk-halves); each block sums 1024 kk (16 iters).
// No-max softmax is additive over kk: blocks write unnormalized bf16 O
// partials + fp32 l partials; combine kernel finishes normalization.
// LDS: K dbuf 2x8KB | V dbuf 2x8KB | P 8x4KB = 64 KB -> 2 blocks/CU.
// XOR swizzle (16B granule, key=row&7) on K/V/P -> ~no bank conflicts.
// No min-waves launch bound (R6 lesson: (512,4) caused scratch spills).
// ---------------------------------------------------------------------------
__global__ __launch_bounds__(512) void flash_attn_mfma(
    const ushort_t* __restrict__ Q, const ushort_t* __restrict__ K,
    const ushort_t* __restrict__ Vt, ushort_t* __restrict__ Opart,
    float* __restrict__ Lpart)
{
    __shared__ __align__(16) ushort_t lds[32768];   // 64 KB

    const int tid  = threadIdx.x;
    const int lane = tid & 63;
    const int w    = tid >> 6;     // 0..7
    const int l15  = lane & 15;
    const int quad = lane >> 4;
    const int key  = l15 & 7;

    const int bh = blockIdx.x;     // XCD locality
    const int b  = bh >> 3;
    const int h  = bh & 7;
    const int q0 = blockIdx.y * 256;
    const int z  = blockIdx.z;     // kk half
    const int kk0 = z * (SEQ / 2);

    const ushort_t* Qb = Q  + (size_t)bh * SEQ * HDIM;
    const ushort_t* Kb = K  + (size_t)bh * SEQ * HDIM + (size_t)kk0 * HDIM;
    const ushort_t* Vb = Vt + (size_t)bh * HDIM * SEQ + kk0;

    // Q B-frags for q = q0 + w*32 + {l15, 16+l15}
    short8 qfA0, qfA1, qfB0, qfB1;
    {
        const ushort_t* qa = Qb + (size_t)(q0 + w * 32 + l15) * HDIM + quad * 8;
        qfA0 = *(const short8*)(qa);
        qfA1 = *(const short8*)(qa + 32);
        qfB0 = *(const short8*)(qa + 16 * HDIM);
        qfB1 = *(const short8*)(qa + 16 * HDIM + 32);
    }

    float lA = 0.f, lB = 0.f;
    floatx4 ofA[4], ofB[4];
#pragma unroll
    for (int t = 0; t < 4; ++t) { ofA[t] = (floatx4)0.0f; ofB[t] = (floatx4)0.0f; }

    // staging: 512 threads, one K short8 + one V short8 each (64x64 tiles)
    const int srow = tid >> 3;        // 0..63
    const int sg   = tid & 7;
    const ushort_t* gK = Kb + (size_t)srow * HDIM + sg * 8;
    const ushort_t* gV = Vb + (size_t)srow * SEQ + sg * 8;
    const int sofs = srow * 64 + (sg ^ (srow & 7)) * 8;   // swizzled in-tile ofs

    ushort_t* Pw = lds + 16384 + w * 2048;                // [32 q][64 kk] swizzled

    short8 kr = *(const short8*)(gK);
    short8 vr = *(const short8*)(gV);

    for (int it = 0; it < 16; ++it) {
        const int buf = it & 1;
        *(short8*)&lds[buf * 4096 + sofs]        = kr;
        *(short8*)&lds[8192 + buf * 4096 + sofs] = vr;
        __syncthreads();

        if (it < 15) {
            kr = *(const short8*)(gK + (size_t)(it + 1) * 64 * HDIM);
            vr = *(const short8*)(gV + (it + 1) * 64);
        }

        // ---- S^T = K . Q^T for both q sets ----
        floatx4 saccA[4], saccB[4];
#pragma unroll
        for (int t = 0; t < 4; ++t) {
            const int kb = buf * 4096 + (t * 16 + l15) * 64;
            const short8 kf0 = *(const short8*)&lds[kb + (quad ^ key) * 8];
            const short8 kf1 = *(const short8*)&lds[kb + ((quad + 4) ^ key) * 8];
            floatx4 a = (floatx4)0.0f, bb = (floatx4)0.0f;
            a  = __builtin_amdgcn_mfma_f32_16x16x32_bf16(kf0, qfA0, a, 0, 0, 0);
            a  = __builtin_amdgcn_mfma_f32_16x16x32_bf16(kf1, qfA1, a, 0, 0, 0);
            bb = __builtin_amdgcn_mfma_f32_16x16x32_bf16(kf0, qfB0, bb, 0, 0, 0);
            bb = __builtin_amdgcn_mfma_f32_16x16x32_bf16(kf1, qfB1, bb, 0, 0, 0);
            saccA[t] = a;
            saccB[t] = bb;
        }

        // ---- no-max softmax + bf16 pack into swizzled P strips ----
        float rsA = 0.f, rsB = 0.f;
#pragma unroll
        for (int t = 0; t < 4; ++t) {
            float pa[4], pb[4];
#pragma unroll
            for (int r = 0; r < 4; ++r) {
                pa[r] = exp2f(saccA[t][r]); rsA += pa[r];
                pb[r] = exp2f(saccB[t][r]); rsB += pb[r];
            }
            const int pofs = ((2 * t + (quad >> 1)) ^ key) * 8 + (quad & 1) * 4;
            {
                const unsigned u0 = __float_as_uint(pa[0]) + 0x8000u;
                const unsigned u1 = __float_as_uint(pa[1]) + 0x8000u;
                const unsigned u2 = __float_as_uint(pa[2]) + 0x8000u;
                const unsigned u3 = __float_as_uint(pa[3]) + 0x8000u;
                const unsigned lo = __builtin_amdgcn_perm(u1, u0, 0x07060302u);
                const unsigned hi = __builtin_amdgcn_perm(u3, u2, 0x07060302u);
                *(unsigned long long*)&Pw[l15 * 64 + pofs] =
                    ((unsigned long long)hi << 32) | lo;
            }
            {
                const unsigned u0 = __float_as_uint(pb[0]) + 0x8000u;
                const unsigned u1 = __float_as_uint(pb[1]) + 0x8000u;
                const unsigned u2 = __float_as_uint(pb[2]) + 0x8000u;
                const unsigned u3 = __float_as_uint(pb[3]) + 0x8000u;
                const unsigned lo = __builtin_amdgcn_perm(u1, u0, 0x07060302u);
                const unsigned hi = __builtin_amdgcn_perm(u3, u2, 0x07060302u);
                *(unsigned long long*)&Pw[(16 + l15) * 64 + pofs] =
                    ((unsigned long long)hi << 32) | lo;
            }
        }
        lA += rsA;
        lB += rsB;
        asm volatile("s_waitcnt lgkmcnt(0)" ::: "memory");

        const short8 pfA0 = *(const short8*)&Pw[l15 * 64 + (quad ^ key) * 8];
        const short8 pfA1 = *(const short8*)&Pw[l15 * 64 + ((quad + 4) ^ key) * 8];
        const short8 pfB0 = *(const short8*)&Pw[(16 + l15) * 64 + (quad ^ key) * 8];
        const short8 pfB1 = *(const short8*)&Pw[(16 + l15) * 64 + ((quad + 4) ^ key) * 8];

        // ---- O^T += V^T . P^T ----
#pragma unroll
        for (int t = 0; t < 4; ++t) {
            const int vb2 = 8192 + buf * 4096 + (t * 16 + l15) * 64;
            const short8 vf0 = *(const short8*)&lds[vb2 + (quad ^ key) * 8];
            const short8 vf1 = *(const short8*)&lds[vb2 + ((quad + 4) ^ key) * 8];
            ofA[t] = __builtin_amdgcn_mfma_f32_16x16x32_bf16(vf0, pfA0, ofA[t], 0, 0, 0);
            ofA[t] = __builtin_amdgcn_mfma_f32_16x16x32_bf16(vf1, pfA1, ofA[t], 0, 0, 0);
            ofB[t] = __builtin_amdgcn_mfma_f32_16x16x32_bf16(vf0, pfB0, ofB[t], 0, 0, 0);
            ofB[t] = __builtin_amdgcn_mfma_f32_16x16x32_bf16(vf1, pfB1, ofB[t], 0, 0, 0);
        }
    }

    // ---- reduce l across quads; write unnormalized partials ----
    lA += __shfl_xor(lA, 16); lA += __shfl_xor(lA, 32);
    lB += __shfl_xor(lB, 16); lB += __shfl_xor(lB, 32);

    const int sA = q0 + w * 32 + l15;
    ushort_t* arowA = Opart + (size_t)z * MROWS * HID
                    + ((size_t)(b * SEQ + sA)) * HID + h * HDIM;
    ushort_t* arowB = arowA + (size_t)16 * HID;
#pragma unroll
    for (int t = 0; t < 4; ++t) {
        short4v pkA, pkB;
#pragma unroll
        for (int r = 0; r < 4; ++r) {
            pkA[r] = (short)bf16_rne(ofA[t][r]);
            pkB[r] = (short)bf16_rne(ofB[t][r]);
        }
        *(short4v*)&arowA[t * 16 + quad * 4] = pkA;
        *(short4v*)&arowB[t * 16 + quad * 4] = pkB;
    }
    if (quad == 0) {
        Lpart[(size_t)(z * 32 + bh) * SEQ + sA]      = lA;
        Lpart[(size_t)(z * 32 + bh) * SEQ + sA + 16] = lB;
    }
}

// ---------------------------------------------------------------------------
// Kernel 2b: combine kk-half partials: Att = (O0+O1) / (l0+l1), bf16.
// ---------------------------------------------------------------------------
__global__ __launch_bounds__(256) void combine_halves(
    const ushort_t* __restrict__ Opart, const float* __restrict__ Lpart,
    ushort_t* __restrict__ Att)
{
    const int idx = blockIdx.x * 256 + threadIdx.x;   // 0..524287
    const int m  = idx >> 6;          // row 0..8191
    const int c0 = (idx & 63) * 8;    // col segment
    const int b = m >> 11;
    const int s = m & 2047;
    const int h = c0 >> 6;
    const int bh = b * 8 + h;

    const float l = Lpart[(size_t)bh * SEQ + s] +
                    Lpart[(size_t)(32 + bh) * SEQ + s];
    const float inv = 1.f / l;

    const short8 o0 = *(const short8*)&Opart[(size_t)m * HID + c0];
    const short8 o1 = *(const short8*)&Opart[(size_t)MROWS * HID + (size_t)m * HID + c0];
    short8 o;
#pragma unroll
    for (int j = 0; j < 8; ++j) {
        const float f = (bf16_to_f((ushort_t)o0[j]) + bf16_to_f((ushort_t)o1[j])) * inv;
        o[j] = (short)bf16_rne(f);
    }
    *(short8*)&Att[(size_t)m * HID + c0] = o;
}

// ---------------------------------------------------------------------------
// Kernel 3: output projection, bf16 MFMA.
// ---------------------------------------------------------------------------
__global__ __launch_bounds__(256) void out_gemm_mfma(
    const ushort_t* __restrict__ Attb, const ushort_t* __restrict__ Wot,
    const float* __restrict__ bo, float* __restrict__ Y)
{
    __shared__ __align__(16) ushort_t As[128 * 64];
    __shared__ __align__(16) ushort_t Bs[128 * 64];

    const int m0 = blockIdx.y * 128;
    const int n0 = blockIdx.x * 128;

    floatx4 acc[4][4];
#pragma unroll
    for (int i = 0; i < 4; ++i)
#pragma unroll
        for (int j = 0; j < 4; ++j) acc[i][j] = (floatx4)0.0f;

    gemm128<HID, true>(Attb, Wot, m0, n0, As, Bs, acc);

    const int lane = threadIdx.x & 63;
    const int w    = threadIdx.x >> 6;
    const int l15  = lane & 15;
    const int quad = lane >> 4;
    const int wrow = w >> 1;
    const int wcol = w & 1;

#pragma unroll
    for (int mi = 0; mi < 4; ++mi) {
        const int m = m0 + wrow * 64 + mi * 16 + l15;
#pragma unroll
        for (int ni = 0; ni < 4; ++ni) {
            const int nb = n0 + wcol * 64 + ni * 16 + quad * 4;
            const floatx4 b4 = *(const floatx4*)(bo + nb);
            floatx4 o;
#pragma unroll
            for (int r = 0; r < 4; ++r) o[r] = acc[mi][ni][r] + b4[r];
            *(floatx4*)&Y[(size_t)m * VDIM + nb] = o;
        }
    }
}

// ---------------------------------------------------------------------------
extern "C" void kernel_launch(void* const* d_in, const int* in_sizes, int n_in,
                              void* d_out, int out_size, void* d_ws, size_t ws_size,
                              hipStream_t stream)
{
    const float* text = (const float*)d_in[0];
    const float* Wq = (const float*)d_in[1];
    const float* bq = (const float*)d_in[2];
    const float* Wk = (const float*)d_in[3];
    const float* bk = (const float*)d_in[4];
    const float* Wv = (const float*)d_in[5];
    const float* bv = (const float*)d_in[6];
    const float* Wo = (const float*)d_in[7];
    const float* bo = (const float*)d_in[8];
    float* out = (float*)d_out;

    // ws layout (ushorts): Xb(6.29M, later aliased by Attb) | Wqkvt | Wot |
    //   Q | K | Vt | Opart(2x4.19M) | Lpart(fp32 131072) -> ~58.6 MB
    ushort_t* Xb    = (ushort_t*)d_ws;
    ushort_t* Wqkvt = Xb + (size_t)MROWS * TDIM;
    ushort_t* Wot   = Wqkvt + (size_t)NQKV * TDIM;
    ushort_t* Qw    = Wot + (size_t)VDIM * HID;
    ushort_t* Kw    = Qw + (size_t)MROWS * HID;
    ushort_t* Vtw   = Kw + (size_t)MROWS * HID;
    ushort_t* Opart = Vtw + (size_t)MROWS * HID;
    float*    Lpart = (float*)(Opart + (size_t)2 * MROWS * HID);
    ushort_t* Attb  = Xb;   // alias: Xb dead after qkv_gemm

    conv_x<<<dim3(MROWS * TDIM / 1024), 256, 0, stream>>>(text, Xb);
    transp_w<<<dim3(24, 24, 4), 256, 0, stream>>>(Wq, Wk, Wv, Wo, Wqkvt, Wot);
    qkv_gemm_mfma<<<dim3(12, 64), 256, 0, stream>>>(Xb, Wqkvt, bq, bk, bv, Qw, Kw, Vtw);
    flash_attn_mfma<<<dim3(32, 8, 2), 512, 0, stream>>>(Qw, Kw, Vtw, Opart, Lpart);
    combine_halves<<<dim3(MROWS * HID / 8 / 256), 256, 0, stream>>>(Opart, Lpart, Attb);
    out_gemm_mfma<<<dim3(6, 64), 256, 0, stream>>>(Attb, Wot, bo, out);
}